// Round 2
// baseline (400.349 us; speedup 1.0000x reference)
//
#include <hip/hip_runtime.h>
#include <hip/hip_bf16.h>
#include <cstdint>
#include <cstddef>

#define BSZ 8
#define NN 2048
#define HH 512

typedef __attribute__((ext_vector_type(4))) float f32x4;
typedef __attribute__((ext_vector_type(8))) short short8;
typedef __attribute__((ext_vector_type(4))) unsigned short us4;
typedef __attribute__((ext_vector_type(8))) unsigned short us8;

static __device__ __forceinline__ unsigned short f2bf(float f) {
    uint32_t u = __builtin_bit_cast(uint32_t, f);
    u += 0x7fffu + ((u >> 16) & 1u);
    return (unsigned short)(u >> 16);
}

static __device__ __forceinline__ void async16(const unsigned short* g, unsigned short* l) {
    __builtin_amdgcn_global_load_lds(
        (const __attribute__((address_space(1))) void*)g,
        (__attribute__((address_space(3))) void*)l, 16, 0, 0);
}

// ---------------- K0: effective q/k weights: wq[h] = sum_o fc_w[o,h]*q_w[o] ------
__global__ __launch_bounds__(256) void eff_w_kernel(
    const float* __restrict__ fc_w, const float* __restrict__ fc_b,
    const float* __restrict__ q_w, const float* __restrict__ q_b,
    const float* __restrict__ k_w, const float* __restrict__ k_b,
    float* __restrict__ wq, float* __restrict__ wk, float* __restrict__ bqk) {
    int h = blockIdx.x * 256 + threadIdx.x;
    float sq = 0.f, sk = 0.f;
    for (int o = 0; o < HH; ++o) {
        float w = fc_w[o * HH + h];
        sq += w * q_w[o];
        sk += w * k_w[o];
    }
    wq[h] = sq; wk[h] = sk;
    if (blockIdx.x == 0) {
        int t = threadIdx.x;
        float bq = fc_b[t] * q_w[t] + fc_b[t + 256] * q_w[t + 256];
        float bk = fc_b[t] * k_w[t] + fc_b[t + 256] * k_w[t + 256];
        for (int off = 32; off; off >>= 1) {
            bq += __shfl_down(bq, off, 64);
            bk += __shfl_down(bk, off, 64);
        }
        __shared__ float rb[8];
        int wv = t >> 6, ln = t & 63;
        if (ln == 0) { rb[wv] = bq; rb[4 + wv] = bk; }
        __syncthreads();
        if (t == 0) bqk[0] = rb[0] + rb[1] + rb[2] + rb[3] + q_b[0];
        if (t == 1) bqk[1] = rb[4] + rb[5] + rb[6] + rb[7] + k_b[0];
    }
}

// ---------------- K1: prep = fused (qk scalars + feats->bf16) and fcw->bf16 -------
// blocks [0,4096): 4 rows each (one wave per row): read fp32 feats row, emit bf16
//                  copy + q/k dot products.
// blocks [4096,4160): convert fc_w (512x512) to bf16.
__global__ __launch_bounds__(256) void prep_kernel(
    const float* __restrict__ feats, const float* __restrict__ fc_w,
    const float* __restrict__ wq, const float* __restrict__ wk,
    const float* __restrict__ bqk,
    unsigned short* __restrict__ feats_bf, unsigned short* __restrict__ fcw_bf,
    float* __restrict__ qv, float* __restrict__ kv) {
    const int bid = blockIdx.x;
    const int t = threadIdx.x;
    if (bid < 4096) {
        __shared__ float swq[HH], swk[HH];
        swq[t] = wq[t]; swq[t + 256] = wq[t + 256];
        swk[t] = wk[t]; swk[t + 256] = wk[t + 256];
        __syncthreads();
        const int wave = t >> 6, lane = t & 63;
        const int row = bid * 4 + wave;
        const float* fr = feats + (size_t)row * HH + lane * 8;
        f32x4 v0 = *(const f32x4*)fr;
        f32x4 v1 = *(const f32x4*)(fr + 4);
        us8 o;
#pragma unroll
        for (int c = 0; c < 4; ++c) { o[c] = f2bf(v0[c]); o[4 + c] = f2bf(v1[c]); }
        *(us8*)(feats_bf + (size_t)row * HH + lane * 8) = o;
        const int base = lane * 8;
        float sq = 0.f, sk = 0.f;
#pragma unroll
        for (int c = 0; c < 4; ++c) { sq += v0[c] * swq[base + c];     sk += v0[c] * swk[base + c]; }
#pragma unroll
        for (int c = 0; c < 4; ++c) { sq += v1[c] * swq[base + 4 + c]; sk += v1[c] * swk[base + 4 + c]; }
        for (int off = 32; off; off >>= 1) {
            sq += __shfl_down(sq, off, 64);
            sk += __shfl_down(sk, off, 64);
        }
        if (lane == 0) { qv[row] = sq + bqk[0]; kv[row] = sk + bqk[1]; }
    } else {
        const int c = bid - 4096;            // 0..63
        const int base = c * 1024 + t;       // in f32x4 units
#pragma unroll
        for (int j = 0; j < 4; ++j) {
            const int i = base + j * 256;
            f32x4 v = ((const f32x4*)fc_w)[i];
            us4 o;
#pragma unroll
            for (int cc = 0; cc < 4; ++cc) o[cc] = f2bf(v[cc]);
            ((us4*)fcw_bf)[i] = o;
        }
    }
}

// ---------------- K2 mega: gemm_fp (0..511) | build_w (512..16895) | out=feats ----
__global__ __launch_bounds__(256) void mega_kernel(
    const unsigned short* __restrict__ A, const unsigned short* __restrict__ Bt,
    const float* __restrict__ fc_b, unsigned short* __restrict__ fpT,
    const float* __restrict__ adj, const float* __restrict__ qv,
    const float* __restrict__ kvv, unsigned short* __restrict__ Wd,
    float* __restrict__ rZ, const float* __restrict__ feats,
    float* __restrict__ out) {
    const int bid = blockIdx.x;
    const int tid = threadIdx.x;
    if (bid < 512) {
        // ---- gemm_fp: fpT[b][o][i] = sum_h feats[b,i,h]*fc_w[o,h] + fc_b[o] ----
        __shared__ alignas(16) unsigned short As[128 * 32];
        __shared__ alignas(16) unsigned short Bs[128 * 32];
        const int wave = tid >> 6, lane = tid & 63;
        const int wi = wave >> 1, wj = wave & 1;
        const int n0 = (bid & 3) * 128;
        const int i0 = (bid >> 2) * 128;
        const int K = HH;
        f32x4 acc[4][4];
#pragma unroll
        for (int a = 0; a < 4; ++a)
#pragma unroll
            for (int b = 0; b < 4; ++b) acc[a][b] = (f32x4)(0.f);
        const int lrow = lane >> 2;
        const int lseg = (lane & 3) * 8;
        const int fro = (lane & 15) * 32 + (lane >> 4) * 8;
        for (int k0 = 0; k0 < K; k0 += 32) {
            __syncthreads();
            {
                const int c0 = wave * 2;
                const unsigned short* ga = A + (size_t)(i0 + c0 * 16 + lrow) * K + k0 + lseg;
                async16(ga, &As[(c0 * 16) * 32]);
                async16(ga + (size_t)16 * K, &As[(c0 * 16 + 16) * 32]);
                const unsigned short* gb = Bt + (size_t)(n0 + c0 * 16 + lrow) * K + k0 + lseg;
                async16(gb, &Bs[(c0 * 16) * 32]);
                async16(gb + (size_t)16 * K, &Bs[(c0 * 16 + 16) * 32]);
            }
            __syncthreads();
            short8 af[4], bf[4];
#pragma unroll
            for (int tt = 0; tt < 4; ++tt) af[tt] = *(const short8*)&As[(wi * 64 + tt * 16) * 32 + fro];
#pragma unroll
            for (int tt = 0; tt < 4; ++tt) bf[tt] = *(const short8*)&Bs[(wj * 64 + tt * 16) * 32 + fro];
#pragma unroll
            for (int it = 0; it < 4; ++it)
#pragma unroll
                for (int jt = 0; jt < 4; ++jt)
                    acc[it][jt] = __builtin_amdgcn_mfma_f32_16x16x32_bf16(af[it], bf[jt], acc[it][jt], 0, 0, 0);
        }
        const int b = i0 >> 11;
        const int il = i0 & 2047;
#pragma unroll
        for (int jt = 0; jt < 4; ++jt) {
            const int col = n0 + wj * 64 + jt * 16 + (lane & 15);
            const float cb = fc_b[col];
#pragma unroll
            for (int it = 0; it < 4; ++it) {
                const int rb = wi * 64 + it * 16 + ((lane >> 4) << 2);
                us4 o;
#pragma unroll
                for (int r = 0; r < 4; ++r) o[r] = f2bf(acc[it][jt][r] + cb);
                *(us4*)(fpT + ((size_t)b * HH + col) * NN + il + rb) = o;
            }
        }
    } else if (bid < 512 + 16384) {
        // ---- build_w: W[b,i,j] = adj * exp(lrelu(q_i+k_j)), rZ = 1/rowsum ----
        const int row = bid - 512;           // b*N + i
        const int b = row >> 11;
        const float qi = qv[row];
        const float* arow = adj + (size_t)row * NN;
        const float* krow = kvv + (b << 11);
        unsigned short* wrow = Wd + (size_t)row * NN;
        float z = 0.f;
#pragma unroll
        for (int rep = 0; rep < 2; ++rep) {
            const int j = rep * 1024 + tid * 4;
            f32x4 a = *(const f32x4*)(arow + j);
            f32x4 kk = *(const f32x4*)(krow + j);
            us4 o;
#pragma unroll
            for (int c = 0; c < 4; ++c) {
                float s = qi + kk[c];
                s = (s >= 0.f) ? s : 0.01f * s;
                float wv = a[c] * __expf(s);
                z += wv;
                o[c] = f2bf(wv);
            }
            *(us4*)(wrow + j) = o;
        }
        for (int off = 32; off; off >>= 1) z += __shfl_down(z, off, 64);
        __shared__ float zr[4];
        if ((tid & 63) == 0) zr[tid >> 6] = z;
        __syncthreads();
        if (tid == 0) rZ[row] = 1.0f / (zr[0] + zr[1] + zr[2] + zr[3]);
    } else {
        // ---- out_init: out = feats (residual base for atomic split-K) ----
        const int c = bid - 16896;           // 0..2047
        const int base = c * 1024 + tid;     // in f32x4 units
#pragma unroll
        for (int j = 0; j < 4; ++j) {
            const int i = base + j * 256;
            ((f32x4*)out)[i] = ((const f32x4*)feats)[i];
        }
    }
}

// ---------------- K3: split-K gemm_out, atomic accumulate into out ----------------
// out[b,i,h] += (sum_{j in half} W[b,i,j]*fpT[b,h,j]) * rZ_i
__global__ __launch_bounds__(256) void gemm_out_kernel(
    const unsigned short* __restrict__ Wd, const unsigned short* __restrict__ fpT,
    const float* __restrict__ rZ, float* __restrict__ out) {
    __shared__ alignas(16) unsigned short As[128 * 32];
    __shared__ alignas(16) unsigned short Bs[128 * 32];
    const int tid = threadIdx.x;
    const int wave = tid >> 6, lane = tid & 63;
    const int wi = wave >> 1, wj = wave & 1;
    const int bid = blockIdx.x;
    const int b = bid & 7;               // batch == XCD for L2 locality
    const int r8 = bid >> 3;             // 0..127
    const int kh = r8 & 1;               // K half
    const int t6 = r8 >> 1;              // 0..63
    const int i0 = (t6 >> 2) * 128;
    const int n0 = (t6 & 3) * 128;
    const int K = NN;
    const unsigned short* A = Wd + (size_t)b * NN * NN;
    const unsigned short* Bt = fpT + (size_t)b * HH * NN;

    f32x4 acc[4][4];
#pragma unroll
    for (int a = 0; a < 4; ++a)
#pragma unroll
        for (int c = 0; c < 4; ++c) acc[a][c] = (f32x4)(0.f);

    const int lrow = lane >> 2;
    const int lseg = (lane & 3) * 8;
    const int fro = (lane & 15) * 32 + (lane >> 4) * 8;

    const int kbeg = kh << 10;
    for (int k0 = kbeg; k0 < kbeg + 1024; k0 += 32) {
        __syncthreads();
        {
            const int c0 = wave * 2;
            const unsigned short* ga = A + (size_t)(i0 + c0 * 16 + lrow) * K + k0 + lseg;
            async16(ga, &As[(c0 * 16) * 32]);
            async16(ga + (size_t)16 * K, &As[(c0 * 16 + 16) * 32]);
            const unsigned short* gb = Bt + (size_t)(n0 + c0 * 16 + lrow) * K + k0 + lseg;
            async16(gb, &Bs[(c0 * 16) * 32]);
            async16(gb + (size_t)16 * K, &Bs[(c0 * 16 + 16) * 32]);
        }
        __syncthreads();
        short8 af[4], bf[4];
#pragma unroll
        for (int t = 0; t < 4; ++t) af[t] = *(const short8*)&As[(wi * 64 + t * 16) * 32 + fro];
#pragma unroll
        for (int t = 0; t < 4; ++t) bf[t] = *(const short8*)&Bs[(wj * 64 + t * 16) * 32 + fro];
#pragma unroll
        for (int it = 0; it < 4; ++it)
#pragma unroll
            for (int jt = 0; jt < 4; ++jt)
                acc[it][jt] = __builtin_amdgcn_mfma_f32_16x16x32_bf16(af[it], bf[jt], acc[it][jt], 0, 0, 0);
    }

    // epilogue: scale by 1/Z, atomic-accumulate onto residual-initialized out
#pragma unroll
    for (int it = 0; it < 4; ++it) {
        const int rb = i0 + wi * 64 + it * 16 + ((lane >> 4) << 2);
        f32x4 rz4 = *(const f32x4*)(rZ + (b << 11) + rb);
#pragma unroll
        for (int jt = 0; jt < 4; ++jt) {
            const int col = n0 + wj * 64 + jt * 16 + (lane & 15);
#pragma unroll
            for (int r = 0; r < 4; ++r) {
                const size_t idx = ((size_t)(b << 11) + rb + r) * HH + col;
                unsafeAtomicAdd(&out[idx], acc[it][jt][r] * rz4[r]);
            }
        }
    }
}

extern "C" void kernel_launch(void* const* d_in, const int* in_sizes, int n_in,
                              void* d_out, int out_size, void* d_ws, size_t ws_size,
                              hipStream_t stream) {
    const float* feats = (const float*)d_in[0];
    const float* adj   = (const float*)d_in[1];
    const float* fc_w  = (const float*)d_in[2];
    const float* fc_b  = (const float*)d_in[3];
    const float* q_w   = (const float*)d_in[4];
    const float* q_b   = (const float*)d_in[5];
    const float* k_w   = (const float*)d_in[6];
    const float* k_b   = (const float*)d_in[7];
    float* out = (float*)d_out;

    char* w = (char*)d_ws;
    auto alloc = [&](size_t bytes) {
        char* p = w;
        w += (bytes + 255) & ~(size_t)255;
        return p;
    };
    unsigned short* feats_bf = (unsigned short*)alloc((size_t)BSZ * NN * HH * 2); // 16.8 MB
    unsigned short* fcw_bf   = (unsigned short*)alloc((size_t)HH * HH * 2);       // 0.5 MB
    float* wq  = (float*)alloc(HH * 4);
    float* wk  = (float*)alloc(HH * 4);
    float* bqk = (float*)alloc(256);
    float* qv  = (float*)alloc((size_t)BSZ * NN * 4);
    float* kv  = (float*)alloc((size_t)BSZ * NN * 4);
    float* rZ  = (float*)alloc((size_t)BSZ * NN * 4);
    unsigned short* fpT = (unsigned short*)alloc((size_t)BSZ * HH * NN * 2);      // 16.8 MB
    unsigned short* Wd  = (unsigned short*)alloc((size_t)BSZ * NN * NN * 2);      // 67 MB

    eff_w_kernel<<<2, 256, 0, stream>>>(fc_w, fc_b, q_w, q_b, k_w, k_b, wq, wk, bqk);
    prep_kernel<<<4096 + 64, 256, 0, stream>>>(feats, fc_w, wq, wk, bqk,
                                               feats_bf, fcw_bf, qv, kv);
    mega_kernel<<<512 + 16384 + 2048, 256, 0, stream>>>(feats_bf, fcw_bf, fc_b, fpT,
                                                        adj, qv, kv, Wd, rZ, feats, out);
    gemm_out_kernel<<<BSZ * (NN / 128) * (HH / 128) * 2, 256, 0, stream>>>(Wd, fpT, rZ, out);
}

// Round 3
// 337.418 us; speedup vs baseline: 1.1865x; 1.1865x over previous
//
#include <hip/hip_runtime.h>
#include <hip/hip_bf16.h>
#include <cstdint>
#include <cstddef>

#define BSZ 8
#define NN 2048
#define HH 512
#define MROWS (BSZ * NN)   // 16384

typedef __attribute__((ext_vector_type(4))) float f32x4;
typedef __attribute__((ext_vector_type(8))) short short8;
typedef __attribute__((ext_vector_type(4))) unsigned short us4;

static __device__ __forceinline__ unsigned short f2bf(float f) {
    uint32_t u = __builtin_bit_cast(uint32_t, f);
    u += 0x7fffu + ((u >> 16) & 1u);
    return (unsigned short)(u >> 16);
}

static __device__ __forceinline__ void async16(const unsigned short* g, unsigned short* l) {
    __builtin_amdgcn_global_load_lds(
        (const __attribute__((address_space(1))) void*)g,
        (__attribute__((address_space(3))) void*)l, 16, 0, 0);
}

// =====================================================================================
// K1: blocks [0,512): gemm_fp  fpT[b][o][i] = sum_h feats[b,i,h]*fc_w[o,h] + fc_b[o]
//                     (fp32 inputs, in-register bf16 cvt -> LDS), plus per-o-tile
//                     partials qpart/kpart[tile][row] = sum_{o in tile} fp[row][o]*q_w[o].
//     blocks [512,1536): adj (fp32 0/1) -> bitmask, 8 cols/byte, 256 B per row.
// =====================================================================================
__global__ __launch_bounds__(256) void k1_kernel(
    const float* __restrict__ feats, const float* __restrict__ fc_w,
    const float* __restrict__ fc_b, const float* __restrict__ q_w,
    const float* __restrict__ k_w, const float* __restrict__ adj,
    unsigned short* __restrict__ fpT, unsigned char* __restrict__ maskb,
    float* __restrict__ qpart, float* __restrict__ kpart) {
    const int bid = blockIdx.x;
    const int tid = threadIdx.x;
    if (bid < 512) {
        __shared__ alignas(16) unsigned short As[128 * 32];
        __shared__ alignas(16) unsigned short Bs[128 * 32];
        __shared__ float qred[2][128], kred[2][128];
        const int wave = tid >> 6, lane = tid & 63;
        const int wi = wave >> 1, wj = wave & 1;
        const int n0 = (bid & 3) * 128;     // o tile
        const int i0 = (bid >> 2) * 128;    // flat row tile
        const int r0 = tid >> 3;            // 0..31 staging row
        const int c4 = (tid & 7) * 4;       // 0..28 staging col
        const int fro = (lane & 15) * 32 + (lane >> 4) * 8;
        f32x4 acc[4][4];
#pragma unroll
        for (int a = 0; a < 4; ++a)
#pragma unroll
            for (int c = 0; c < 4; ++c) acc[a][c] = (f32x4)(0.f);

        for (int k0 = 0; k0 < HH; k0 += 32) {
            __syncthreads();
#pragma unroll
            for (int m = 0; m < 4; ++m) {
                f32x4 av = *(const f32x4*)&feats[(size_t)(i0 + r0 + 32 * m) * HH + k0 + c4];
                f32x4 bv = *(const f32x4*)&fc_w[(size_t)(n0 + r0 + 32 * m) * HH + k0 + c4];
                us4 oa, ob;
#pragma unroll
                for (int c = 0; c < 4; ++c) { oa[c] = f2bf(av[c]); ob[c] = f2bf(bv[c]); }
                *(us4*)&As[(r0 + 32 * m) * 32 + c4] = oa;
                *(us4*)&Bs[(r0 + 32 * m) * 32 + c4] = ob;
            }
            __syncthreads();
            short8 af[4], bf[4];
#pragma unroll
            for (int t = 0; t < 4; ++t) af[t] = *(const short8*)&As[(wi * 64 + t * 16) * 32 + fro];
#pragma unroll
            for (int t = 0; t < 4; ++t) bf[t] = *(const short8*)&Bs[(wj * 64 + t * 16) * 32 + fro];
#pragma unroll
            for (int it = 0; it < 4; ++it)
#pragma unroll
                for (int jt = 0; jt < 4; ++jt)
                    acc[it][jt] = __builtin_amdgcn_mfma_f32_16x16x32_bf16(af[it], bf[jt], acc[it][jt], 0, 0, 0);
        }

        // per-lane column constants
        int colv[4]; float cbv[4], qwv[4], kwv[4];
#pragma unroll
        for (int jt = 0; jt < 4; ++jt) {
            colv[jt] = n0 + wj * 64 + jt * 16 + (lane & 15);
            cbv[jt] = fc_b[colv[jt]];
            qwv[jt] = q_w[colv[jt]];
            kwv[jt] = k_w[colv[jt]];
        }
        // store fpT (transposed, bf16)
        const int b = i0 >> 11;
        const int il = i0 & 2047;
#pragma unroll
        for (int jt = 0; jt < 4; ++jt) {
#pragma unroll
            for (int it = 0; it < 4; ++it) {
                const int rb = wi * 64 + it * 16 + ((lane >> 4) << 2);
                us4 o;
#pragma unroll
                for (int r = 0; r < 4; ++r) o[r] = f2bf(acc[it][jt][r] + cbv[jt]);
                *(us4*)(fpT + ((size_t)b * HH + colv[jt]) * NN + il + rb) = o;
            }
        }
        // q/k partials: per (it,r) row, sum over this block's 128 o-cols
#pragma unroll
        for (int it = 0; it < 4; ++it) {
#pragma unroll
            for (int r = 0; r < 4; ++r) {
                float pq = 0.f, pk = 0.f;
#pragma unroll
                for (int jt = 0; jt < 4; ++jt) {
                    float v = acc[it][jt][r] + cbv[jt];
                    pq += v * qwv[jt];
                    pk += v * kwv[jt];
                }
                for (int off = 1; off < 16; off <<= 1) {
                    pq += __shfl_xor(pq, off, 64);
                    pk += __shfl_xor(pk, off, 64);
                }
                if ((lane & 15) == 0) {
                    const int rr = wi * 64 + it * 16 + ((lane >> 4) << 2) + r;
                    qred[wj][rr] = pq;
                    kred[wj][rr] = pk;
                }
            }
        }
        __syncthreads();
        if (tid < 128) {
            const size_t o = (size_t)(n0 >> 7) * MROWS + i0 + tid;
            qpart[o] = qred[0][tid] + qred[1][tid];
            kpart[o] = kred[0][tid] + kred[1][tid];
        }
    } else {
        // ---- adj -> bitmask: byte j>>3 bit j&7 = (adj[row][j] != 0) ----
        const int a = bid - 512;             // 0..1023, 16 rows each
        const int wave = tid >> 6, lane = tid & 63;
#pragma unroll
        for (int s = 0; s < 4; ++s) {
            const int row = a * 16 + s * 4 + wave;
            const float* ar = adj + (size_t)row * NN;
#pragma unroll
            for (int p = 0; p < 4; ++p) {
                f32x4 v0 = *(const f32x4*)&ar[p * 512 + lane * 8];
                f32x4 v1 = *(const f32x4*)&ar[p * 512 + lane * 8 + 4];
                float fb = v0[0] + 2.f * v0[1] + 4.f * v0[2] + 8.f * v0[3]
                         + 16.f * v1[0] + 32.f * v1[1] + 64.f * v1[2] + 128.f * v1[3];
                maskb[(size_t)row * 256 + p * 64 + lane] = (unsigned char)(unsigned int)fb;
            }
        }
    }
}

// =====================================================================================
// K2: fused W-build + PV GEMM + softmax-normalize + residual.
// Per block: batch b, 128 rows i, 128 cols h. K-loop over j (BK=32):
//   A-tile (LDS, bf16) = adjbit * exp(lrelu(q_i + k_j)) computed in-register,
//   B-tile (LDS) = fpT via global_load_lds, 16 MFMA. Z accumulated inline.
// =====================================================================================
__global__ __launch_bounds__(256) void fused_pv_kernel(
    const unsigned short* __restrict__ fpT, const unsigned char* __restrict__ maskb,
    const float* __restrict__ qpart, const float* __restrict__ kpart,
    const float* __restrict__ q_b, const float* __restrict__ k_b,
    const float* __restrict__ feats, float* __restrict__ out) {
    __shared__ alignas(16) unsigned short As[128 * 32];
    __shared__ alignas(16) unsigned short Bs[128 * 32];
    __shared__ float kLDS[NN];
    __shared__ float qLDS[128];
    __shared__ float zbuf[4][32][8];
    __shared__ float rzl[128];
    const int tid = threadIdx.x;
    const int wave = tid >> 6, lane = tid & 63;
    const int wi = wave >> 1, wj = wave & 1;
    const int bid = blockIdx.x;
    const int b = bid & 7;               // batch == XCD slot for fpT L2 locality
    const int t6 = bid >> 3;             // 0..63
    const int i0 = (t6 >> 2) * 128;      // row tile within batch
    const int n0 = (t6 & 3) * 128;       // h tile
    const size_t rowbase = (size_t)b * NN + i0;

    // prologue: k scalars (all 2048) and q scalars (128 rows) into LDS
    {
        const float kb = k_b[0], qb = q_b[0];
#pragma unroll
        for (int s = 0; s < 8; ++s) {
            const int j = s * 256 + tid;
            const size_t gj = (size_t)b * NN + j;
            kLDS[j] = qpart[0] * 0.f + kpart[gj] + kpart[MROWS + gj]
                    + kpart[2 * MROWS + gj] + kpart[3 * MROWS + gj] + kb;
        }
        if (tid < 128) {
            const size_t gi = rowbase + tid;
            qLDS[tid] = qpart[gi] + qpart[MROWS + gi]
                      + qpart[2 * MROWS + gi] + qpart[3 * MROWS + gi] + qb;
        }
    }
    __syncthreads();

    const int r0 = tid >> 3;            // 0..31
    const int c4 = (tid & 7) * 4;       // 0..28
    float qi[4];
#pragma unroll
    for (int m = 0; m < 4; ++m) qi[m] = qLDS[r0 + 32 * m];
    float z[4] = {0.f, 0.f, 0.f, 0.f};

    const unsigned short* Bt = fpT + (size_t)b * HH * NN;
    const uint32_t* mk = (const uint32_t*)maskb;
    const int lrow = lane >> 2, lseg = (lane & 3) * 8;
    const int fro = (lane & 15) * 32 + (lane >> 4) * 8;

    f32x4 acc[4][4];
#pragma unroll
    for (int a = 0; a < 4; ++a)
#pragma unroll
        for (int c = 0; c < 4; ++c) acc[a][c] = (f32x4)(0.f);

    // mask prefetch for k0 = 0
    uint32_t mcur[4];
#pragma unroll
    for (int m = 0; m < 4; ++m) mcur[m] = mk[(rowbase + r0 + 32 * m) * 64];

    for (int k0 = 0; k0 < NN; k0 += 32) {
        __syncthreads();
        {
            const int c0 = wave * 2;
            const unsigned short* gb = Bt + (size_t)(n0 + c0 * 16 + lrow) * NN + k0 + lseg;
            async16(gb, &Bs[(c0 * 16) * 32]);
            async16(gb + (size_t)16 * NN, &Bs[(c0 * 16 + 16) * 32]);
        }
        // prefetch next iteration's mask dwords
        uint32_t mnext[4];
        if (k0 + 32 < NN) {
#pragma unroll
            for (int m = 0; m < 4; ++m)
                mnext[m] = mk[(rowbase + r0 + 32 * m) * 64 + ((k0 + 32) >> 5)];
        }
        // transform: W tile -> As (bf16)
        const f32x4 kv = *(const f32x4*)&kLDS[k0 + c4];
#pragma unroll
        for (int m = 0; m < 4; ++m) {
            const uint32_t nib = (mcur[m] >> c4) & 0xFu;
            us4 o;
#pragma unroll
            for (int c = 0; c < 4; ++c) {
                float s = qi[m] + kv[c];
                s = (s >= 0.f) ? s : 0.01f * s;
                const float e = __expf(s);
                const float wv = ((nib >> c) & 1u) ? e : 0.f;
                z[m] += wv;
                o[c] = f2bf(wv);
            }
            *(us4*)&As[(r0 + 32 * m) * 32 + c4] = o;
        }
        __syncthreads();
        short8 af[4], bf[4];
#pragma unroll
        for (int t = 0; t < 4; ++t) af[t] = *(const short8*)&As[(wi * 64 + t * 16) * 32 + fro];
#pragma unroll
        for (int t = 0; t < 4; ++t) bf[t] = *(const short8*)&Bs[(wj * 64 + t * 16) * 32 + fro];
#pragma unroll
        for (int it = 0; it < 4; ++it)
#pragma unroll
            for (int jt = 0; jt < 4; ++jt)
                acc[it][jt] = __builtin_amdgcn_mfma_f32_16x16x32_bf16(af[it], bf[jt], acc[it][jt], 0, 0, 0);
#pragma unroll
        for (int m = 0; m < 4; ++m) mcur[m] = mnext[m];
    }

    // Z reduction across the 8 threads sharing each row
#pragma unroll
    for (int m = 0; m < 4; ++m) zbuf[m][r0][tid & 7] = z[m];
    __syncthreads();
    if (tid < 128) {
        float s = 0.f;
        const float* zp = zbuf[tid >> 5][tid & 31];
#pragma unroll
        for (int j = 0; j < 8; ++j) s += zp[j];
        rzl[tid] = 1.0f / s;
    }
    __syncthreads();

    // epilogue: scale by 1/Z, add residual, plain fp32 stores
#pragma unroll
    for (int it = 0; it < 4; ++it) {
        const int rb = wi * 64 + it * 16 + ((lane >> 4) << 2);
        float rv[4];
#pragma unroll
        for (int r = 0; r < 4; ++r) rv[r] = rzl[rb + r];
#pragma unroll
        for (int jt = 0; jt < 4; ++jt) {
            const int col = n0 + wj * 64 + jt * 16 + (lane & 15);
#pragma unroll
            for (int r = 0; r < 4; ++r) {
                const size_t idx = (rowbase + rb + r) * HH + col;
                out[idx] = acc[it][jt][r] * rv[r] + feats[idx];
            }
        }
    }
}

extern "C" void kernel_launch(void* const* d_in, const int* in_sizes, int n_in,
                              void* d_out, int out_size, void* d_ws, size_t ws_size,
                              hipStream_t stream) {
    const float* feats = (const float*)d_in[0];
    const float* adj   = (const float*)d_in[1];
    const float* fc_w  = (const float*)d_in[2];
    const float* fc_b  = (const float*)d_in[3];
    const float* q_w   = (const float*)d_in[4];
    const float* q_b   = (const float*)d_in[5];
    const float* k_w   = (const float*)d_in[6];
    const float* k_b   = (const float*)d_in[7];
    float* out = (float*)d_out;

    char* w = (char*)d_ws;
    auto alloc = [&](size_t bytes) {
        char* p = w;
        w += (bytes + 255) & ~(size_t)255;
        return p;
    };
    unsigned short* fpT   = (unsigned short*)alloc((size_t)BSZ * HH * NN * 2);  // 16.8 MB
    unsigned char*  maskb = (unsigned char*)alloc((size_t)MROWS * 256);         // 4.2 MB
    float* qpart = (float*)alloc((size_t)4 * MROWS * 4);                        // 256 KB
    float* kpart = (float*)alloc((size_t)4 * MROWS * 4);                        // 256 KB

    k1_kernel<<<512 + 1024, 256, 0, stream>>>(feats, fc_w, fc_b, q_w, k_w, adj,
                                              fpT, maskb, qpart, kpart);
    fused_pv_kernel<<<BSZ * (NN / 128) * (HH / 128), 256, 0, stream>>>(
        fpT, maskb, qpart, kpart, q_b, k_b, feats, out);
}

// Round 5
// 320.069 us; speedup vs baseline: 1.2508x; 1.0542x over previous
//
#include <hip/hip_runtime.h>
#include <hip/hip_bf16.h>
#include <cstdint>
#include <cstddef>

#define BSZ 8
#define NN 2048
#define HH 512
#define MROWS (BSZ * NN)   // 16384
#define LOG2E 1.44269504088896f

typedef __attribute__((ext_vector_type(4))) float f32x4;
typedef __attribute__((ext_vector_type(8))) short short8;
typedef __attribute__((ext_vector_type(4))) unsigned short us4;
typedef __attribute__((ext_vector_type(4))) uint32_t u32x4;

#if __has_builtin(__builtin_amdgcn_exp2f)
#define EXP2(x) __builtin_amdgcn_exp2f(x)
#else
#define EXP2(x) __expf((x) * 0.69314718056f)
#endif

static __device__ __forceinline__ unsigned short f2bf(float f) {
    uint32_t u = __builtin_bit_cast(uint32_t, f);
    u += 0x7fffu + ((u >> 16) & 1u);
    return (unsigned short)(u >> 16);
}

static __device__ __forceinline__ void async16(const unsigned short* g, unsigned short* l) {
    __builtin_amdgcn_global_load_lds(
        (const __attribute__((address_space(1))) void*)g,
        (__attribute__((address_space(3))) void*)l, 16, 0, 0);
}

// =====================================================================================
// K1: blocks [0,512): gemm_fp  fpT[b][o][i] = sum_h feats[b,i,h]*fc_w[o,h] + fc_b[o]
//                     (fp32 inputs, in-register bf16 cvt -> LDS), plus per-o-tile
//                     partials qpart/kpart[tile][row] = sum_{o in tile} fp[row][o]*q_w[o].
//     blocks [512,1536): adj (fp32 0/1) -> bitmask, 8 cols/byte, 256 B per row.
// =====================================================================================
__global__ __launch_bounds__(256) void k1_kernel(
    const float* __restrict__ feats, const float* __restrict__ fc_w,
    const float* __restrict__ fc_b, const float* __restrict__ q_w,
    const float* __restrict__ k_w, const float* __restrict__ adj,
    unsigned short* __restrict__ fpT, unsigned char* __restrict__ maskb,
    float* __restrict__ qpart, float* __restrict__ kpart) {
    const int bid = blockIdx.x;
    const int tid = threadIdx.x;
    if (bid < 512) {
        __shared__ alignas(16) unsigned short As[128 * 32];
        __shared__ alignas(16) unsigned short Bs[128 * 32];
        __shared__ float qred[2][128], kred[2][128];
        const int wave = tid >> 6, lane = tid & 63;
        const int wi = wave >> 1, wj = wave & 1;
        const int n0 = (bid & 3) * 128;     // o tile
        const int i0 = (bid >> 2) * 128;    // flat row tile
        const int r0 = tid >> 3;            // 0..31 staging row
        const int c4 = (tid & 7) * 4;       // 0..28 staging col
        const int fro = (lane & 15) * 32 + (lane >> 4) * 8;
        f32x4 acc[4][4];
#pragma unroll
        for (int a = 0; a < 4; ++a)
#pragma unroll
            for (int c = 0; c < 4; ++c) acc[a][c] = (f32x4)(0.f);

        for (int k0 = 0; k0 < HH; k0 += 32) {
            __syncthreads();
#pragma unroll
            for (int m = 0; m < 4; ++m) {
                f32x4 av = *(const f32x4*)&feats[(size_t)(i0 + r0 + 32 * m) * HH + k0 + c4];
                f32x4 bv = *(const f32x4*)&fc_w[(size_t)(n0 + r0 + 32 * m) * HH + k0 + c4];
                us4 oa, ob;
#pragma unroll
                for (int c = 0; c < 4; ++c) { oa[c] = f2bf(av[c]); ob[c] = f2bf(bv[c]); }
                *(us4*)&As[(r0 + 32 * m) * 32 + c4] = oa;
                *(us4*)&Bs[(r0 + 32 * m) * 32 + c4] = ob;
            }
            __syncthreads();
            short8 af[4], bf[4];
#pragma unroll
            for (int t = 0; t < 4; ++t) af[t] = *(const short8*)&As[(wi * 64 + t * 16) * 32 + fro];
#pragma unroll
            for (int t = 0; t < 4; ++t) bf[t] = *(const short8*)&Bs[(wj * 64 + t * 16) * 32 + fro];
#pragma unroll
            for (int it = 0; it < 4; ++it)
#pragma unroll
                for (int jt = 0; jt < 4; ++jt)
                    acc[it][jt] = __builtin_amdgcn_mfma_f32_16x16x32_bf16(af[it], bf[jt], acc[it][jt], 0, 0, 0);
        }

        int colv[4]; float cbv[4], qwv[4], kwv[4];
#pragma unroll
        for (int jt = 0; jt < 4; ++jt) {
            colv[jt] = n0 + wj * 64 + jt * 16 + (lane & 15);
            cbv[jt] = fc_b[colv[jt]];
            qwv[jt] = q_w[colv[jt]];
            kwv[jt] = k_w[colv[jt]];
        }
        const int b = i0 >> 11;
        const int il = i0 & 2047;
#pragma unroll
        for (int jt = 0; jt < 4; ++jt) {
#pragma unroll
            for (int it = 0; it < 4; ++it) {
                const int rb = wi * 64 + it * 16 + ((lane >> 4) << 2);
                us4 o;
#pragma unroll
                for (int r = 0; r < 4; ++r) o[r] = f2bf(acc[it][jt][r] + cbv[jt]);
                *(us4*)(fpT + ((size_t)b * HH + colv[jt]) * NN + il + rb) = o;
            }
        }
#pragma unroll
        for (int it = 0; it < 4; ++it) {
#pragma unroll
            for (int r = 0; r < 4; ++r) {
                float pq = 0.f, pk = 0.f;
#pragma unroll
                for (int jt = 0; jt < 4; ++jt) {
                    float v = acc[it][jt][r] + cbv[jt];
                    pq += v * qwv[jt];
                    pk += v * kwv[jt];
                }
                for (int off = 1; off < 16; off <<= 1) {
                    pq += __shfl_xor(pq, off, 64);
                    pk += __shfl_xor(pk, off, 64);
                }
                if ((lane & 15) == 0) {
                    const int rr = wi * 64 + it * 16 + ((lane >> 4) << 2) + r;
                    qred[wj][rr] = pq;
                    kred[wj][rr] = pk;
                }
            }
        }
        __syncthreads();
        if (tid < 128) {
            const size_t o = (size_t)(n0 >> 7) * MROWS + i0 + tid;
            qpart[o] = qred[0][tid] + qred[1][tid];
            kpart[o] = kred[0][tid] + kred[1][tid];
        }
    } else {
        // ---- adj -> bitmask ----
        const int a = bid - 512;             // 0..1023, 16 rows each
        const int wave = tid >> 6, lane = tid & 63;
#pragma unroll
        for (int s = 0; s < 4; ++s) {
            const int row = a * 16 + s * 4 + wave;
            const float* ar = adj + (size_t)row * NN;
#pragma unroll
            for (int p = 0; p < 4; ++p) {
                f32x4 v0 = *(const f32x4*)&ar[p * 512 + lane * 8];
                f32x4 v1 = *(const f32x4*)&ar[p * 512 + lane * 8 + 4];
                float fb = v0[0] + 2.f * v0[1] + 4.f * v0[2] + 8.f * v0[3]
                         + 16.f * v1[0] + 32.f * v1[1] + 64.f * v1[2] + 128.f * v1[3];
                maskb[(size_t)row * 256 + p * 64 + lane] = (unsigned char)(unsigned int)fb;
            }
        }
    }
}

// =====================================================================================
// K2 v2: fused W-build + PV GEMM. M=64 rows x N=256 h-cols per block, BK=32.
// W computed once per (row-panel, half-H) -> 2x total recompute (was 4x).
// Transform: exp2 with prescaled q/k, lrelu = fmax(s, .01s), pack via +0x8000 + perm.
// =====================================================================================
__global__ __launch_bounds__(256) void fused_pv_kernel(
    const unsigned short* __restrict__ fpT, const unsigned char* __restrict__ maskb,
    const float* __restrict__ qpart, const float* __restrict__ kpart,
    const float* __restrict__ q_b, const float* __restrict__ k_b,
    const float* __restrict__ feats, float* __restrict__ out) {
    __shared__ alignas(16) unsigned short As[64 * 32];    // 4 KB
    __shared__ alignas(16) unsigned short Bs[256 * 32];   // 16 KB
    __shared__ float kLDS[NN];                            // 8 KB
    __shared__ float qLDS[64];
    __shared__ float zfl[256];
    __shared__ float rzl[64];
    const int tid = threadIdx.x;
    const int wave = tid >> 6, lane = tid & 63;
    const int wi = wave >> 1, wj = wave & 1;
    const int bid = blockIdx.x;
    const int b = bid & 7;               // batch == XCD slot for fpT L2 locality
    const int t6 = bid >> 3;             // 0..63
    const int i0 = (t6 >> 1) * 64;       // row tile within batch
    const int n0 = (t6 & 1) * 256;       // h half
    const size_t rowbase = (size_t)b * NN + i0;

    // prologue: prescaled k (all 2048) and q (64 rows) into LDS
    {
        const float kb = k_b[0], qb = q_b[0];
#pragma unroll
        for (int s = 0; s < 8; ++s) {
            const int j = s * 256 + tid;
            const size_t gj = (size_t)b * NN + j;
            kLDS[j] = (kpart[gj] + kpart[MROWS + gj] + kpart[2 * MROWS + gj]
                     + kpart[3 * MROWS + gj] + kb) * LOG2E;
        }
        if (tid < 64) {
            const size_t gi = rowbase + tid;
            qLDS[tid] = (qpart[gi] + qpart[MROWS + gi] + qpart[2 * MROWS + gi]
                       + qpart[3 * MROWS + gi] + qb) * LOG2E;
        }
    }
    __syncthreads();

    const int r0 = tid >> 2;            // 0..63: W row handled by this thread
    const int c8 = (tid & 3) * 8;       // 8 consecutive K cols
    const float qi = qLDS[r0];
    float z = 0.f;

    const unsigned short* Bt = fpT + (size_t)b * HH * NN;
    const uint32_t* mk = (const uint32_t*)maskb;
    const size_t mrow = (rowbase + r0) * 64;
    const int lrow = lane >> 2, lseg = (lane & 3) * 8;
    const int fro = (lane & 15) * 32 + (lane >> 4) * 8;

    f32x4 acc[2][8];
#pragma unroll
    for (int a = 0; a < 2; ++a)
#pragma unroll
        for (int c = 0; c < 8; ++c) acc[a][c] = (f32x4)(0.f);

    uint32_t mcur = mk[mrow];           // bits for k0 = 0
    for (int k0 = 0; k0 < NN; k0 += 32) {
        __syncthreads();
        // stage B: each wave stages 64 rows (4 chunks of 16)
        {
            const int rbase = wave * 64;
            const unsigned short* gb = Bt + (size_t)(n0 + rbase + lrow) * NN + k0 + lseg;
            async16(gb, &Bs[rbase * 32]);
            async16(gb + (size_t)16 * NN, &Bs[(rbase + 16) * 32]);
            async16(gb + (size_t)32 * NN, &Bs[(rbase + 32) * 32]);
            async16(gb + (size_t)48 * NN, &Bs[(rbase + 48) * 32]);
        }
        uint32_t mnext = 0;
        if (k0 + 32 < NN) mnext = mk[mrow + ((k0 + 32) >> 5)];
        // transform: 8 W elements (1 row x 8 cols) -> As
        const f32x4 kv0 = *(const f32x4*)&kLDS[k0 + c8];
        const f32x4 kv1 = *(const f32x4*)&kLDS[k0 + c8 + 4];
        const uint32_t byte8 = (mcur >> c8) & 0xffu;
        float wv[8];
#pragma unroll
        for (int c = 0; c < 8; ++c) {
            float s = qi + (c < 4 ? kv0[c] : kv1[c - 4]);
            s = fmaxf(s, 0.01f * s);
            float e = EXP2(s);
            wv[c] = ((byte8 >> c) & 1u) ? e : 0.f;
            z += wv[c];
        }
        u32x4 pk;
#pragma unroll
        for (int p = 0; p < 4; ++p) {
            uint32_t lo = __builtin_bit_cast(uint32_t, wv[2 * p]) + 0x8000u;
            uint32_t hi = __builtin_bit_cast(uint32_t, wv[2 * p + 1]) + 0x8000u;
            pk[p] = __builtin_amdgcn_perm(hi, lo, 0x07060302u);
        }
        *(u32x4*)&As[r0 * 32 + c8] = pk;   // byte addr = tid*16, linear, conflict-free
        __syncthreads();
        short8 af[2], bf[8];
#pragma unroll
        for (int t = 0; t < 2; ++t) af[t] = *(const short8*)&As[(wi * 32 + t * 16) * 32 + fro];
#pragma unroll
        for (int t = 0; t < 8; ++t) bf[t] = *(const short8*)&Bs[(wj * 128 + t * 16) * 32 + fro];
#pragma unroll
        for (int it = 0; it < 2; ++it)
#pragma unroll
            for (int jt = 0; jt < 8; ++jt)
                acc[it][jt] = __builtin_amdgcn_mfma_f32_16x16x32_bf16(af[it], bf[jt], acc[it][jt], 0, 0, 0);
        mcur = mnext;
    }

    // Z reduction: 4 threads per row
    zfl[tid] = z;
    __syncthreads();
    if (tid < 64) {
        const float* zp = &zfl[tid * 4];
        rzl[tid] = 1.0f / (zp[0] + zp[1] + zp[2] + zp[3]);
    }
    __syncthreads();

    // epilogue: scale by 1/Z, add residual, plain fp32 stores
#pragma unroll
    for (int it = 0; it < 2; ++it) {
        const int rb = wi * 32 + it * 16 + ((lane >> 4) << 2);
        float rv[4];
#pragma unroll
        for (int r = 0; r < 4; ++r) rv[r] = rzl[rb + r];
#pragma unroll
        for (int jt = 0; jt < 8; ++jt) {
            const int col = n0 + wj * 128 + jt * 16 + (lane & 15);
#pragma unroll
            for (int r = 0; r < 4; ++r) {
                const size_t idx = (rowbase + rb + r) * HH + col;
                out[idx] = acc[it][jt][r] * rv[r] + feats[idx];
            }
        }
    }
}

extern "C" void kernel_launch(void* const* d_in, const int* in_sizes, int n_in,
                              void* d_out, int out_size, void* d_ws, size_t ws_size,
                              hipStream_t stream) {
    const float* feats = (const float*)d_in[0];
    const float* adj   = (const float*)d_in[1];
    const float* fc_w  = (const float*)d_in[2];
    const float* fc_b  = (const float*)d_in[3];
    const float* q_w   = (const float*)d_in[4];
    const float* q_b   = (const float*)d_in[5];
    const float* k_w   = (const float*)d_in[6];
    const float* k_b   = (const float*)d_in[7];
    float* out = (float*)d_out;

    char* w = (char*)d_ws;
    auto alloc = [&](size_t bytes) {
        char* p = w;
        w += (bytes + 255) & ~(size_t)255;
        return p;
    };
    unsigned short* fpT   = (unsigned short*)alloc((size_t)BSZ * HH * NN * 2);  // 16.8 MB
    unsigned char*  maskb = (unsigned char*)alloc((size_t)MROWS * 256);         // 4.2 MB
    float* qpart = (float*)alloc((size_t)4 * MROWS * 4);                        // 256 KB
    float* kpart = (float*)alloc((size_t)4 * MROWS * 4);                        // 256 KB

    k1_kernel<<<512 + 1024, 256, 0, stream>>>(feats, fc_w, fc_b, q_w, k_w, adj,
                                              fpT, maskb, qpart, kpart);
    fused_pv_kernel<<<512, 256, 0, stream>>>(
        fpT, maskb, qpart, kpart, q_b, k_b, feats, out);
}